// Round 11
// baseline (134.529 us; speedup 1.0000x reference)
//
#include <hip/hip_runtime.h>
#include <math.h>

// B=64, A=64, MULS=((64,0),(32,1),(16,2)) -> DIM_IN=240, NB=32, H=128, MOUT=112
#define H_ 128
#define NB_ 32

#define INV_STEP 3.1f
#define HALF_PI 1.57079632679489662f
#define INV_SQRT_NB 0.17677669529663689f
#define INV_SQRT_H 0.08838834764831845f
#define NORM0 0.125f
#define NORM1 0.10206207261596575f
#define NORM2 0.11180339887498948f
#define S3 1.7320508075688772f
#define S5 2.23606797749979f
#define S15 3.872983346207417f
#define LN2 0.6931471805599453f

typedef __attribute__((ext_vector_type(8))) _Float16 half8;
typedef __attribute__((ext_vector_type(4))) float f32x4;

__device__ __forceinline__ float ssp_f(float x) {
    float t = 5.0f * x;
    float s = fmaxf(t, 0.0f) + __logf(1.0f + __expf(-fabsf(t)));
    return (s - LN2) * 0.2f;
}
__device__ __forceinline__ float sp_f(float x) {
    float t = 5.0f * x;
    float s = fmaxf(t, 0.0f) + __logf(1.0f + __expf(-fabsf(t)));
    return s * 0.2f;
}

// ---------------------------------------------------------------------------
// pair4: Round-11. Launch accounting over R8/R9/R10 isolated the w2half
// PRE-kernel + its dependency gap as ~25-27 µs of makespan (R8/R10 overhead
// 55-57 µs vs R9's 30 µs; finalize tail is only ~2 µs). R9's fix cost 26 µs
// inside pair4 (B-frags moved to the LDS pipe). This round folds the W2->fp16
// conversion into pair4 but keeps the frags on the VMEM pipe:
//   - Every block redundantly converts all of W2 (64 KB) into the SAME 32 KB
//     global-ws fragment buffer. All writers store identical values -> any
//     interleaving is correct; each block's own writes are drained by the
//     pre-main-loop __syncthreads (compiler emits vmcnt(0) before s_barrier),
//     so its main-loop reads hit its own XCD L2. No cross-block sync needed.
//   - Main loop = R8's proven 77 µs body, byte-identical (global w2f reads
//     on the vmem pipe, 2-b ILP, 128 arch regs, fp16 sH2t transpose,
//     hoisted reduce).
//   - Separate 2 µs finalize kernel (R9-measured config overhead: 30 µs).
//     No counters / no atomics / no fences.
// ---------------------------------------------------------------------------
__global__ __launch_bounds__(256, 2)
void pair4(const float* __restrict__ rep, const float* __restrict__ geom,
           const float* __restrict__ W1, const float* __restrict__ W2,
           const float* __restrict__ W3, _Float16* __restrict__ w2f,
           float* __restrict__ partial) {
    const int bg = blockIdx.x;           // b in [8bg, 8bg+8)
    const int z  = blockIdx.y;
    const int tid = threadIdx.x;
    const int wv = tid >> 6, lane = tid & 63;
    const int m = lane & 15, quad = lane >> 4;

    __shared__ __align__(16) _Float16 sVf[16384];      // 32768 B  [b<8][kt][lane][j]
    __shared__ __align__(16) _Float16 sH2t[4][16][40]; // 5120 B   per-wave [a][h2local+pad]
    __shared__ __align__(16) float sRep[1920];         // 7680 B   8 rep rows
    __shared__ float sYw[4][2][16][8];                 // 4096 B
    __shared__ float sPosA[192];                       // 768 B
    __shared__ float sPosB[24];                        // 96 B
    // total ~50.6 KB; reg-bound 2 blocks/CU

    // ---- W2 -> fp16 B-frags into global ws (replaces the w2half kernel) ----
    // fragment pos = ((kt*8+nt)*64 + ln)*8 + j ; k = kt*32+(ln>>4)*8+j ;
    // n = nt*16+(ln&15). Thread handles 8 (fn,ln) pairs: 8 strided dword
    // reads (L2-hot after first touch) + one coalesced 16 B store each.
    #pragma unroll
    for (int i = 0; i < 8; ++i) {
        const int pr = tid + i * 256;        // 0..2047
        const int ln = pr & 63, fn = pr >> 6;
        const int kt = fn >> 3, nt = fn & 7;
        const int krow = kt * 32 + (ln >> 4) * 8;
        const int n = nt * 16 + (ln & 15);
        const float* src = W2 + krow * 128 + n;
        half8 hv;
        #pragma unroll
        for (int j = 0; j < 8; ++j)
            hv[j] = (_Float16)src[j * 128];
        *reinterpret_cast<half8*>(w2f + (size_t)pr * 8) = hv;
    }

    // ---- startup: stage geom + rep ----
    if (tid < 192) sPosA[tid] = geom[z * 192 + tid];
    else if (tid < 216) sPosB[tid - 192] = geom[((size_t)z * 64 + bg * 8) * 3 + (tid - 192)];
    {
        const float4* src = reinterpret_cast<const float4*>(rep + ((size_t)z * 64 + bg * 8) * 240);
        float4* dst = reinterpret_cast<float4*>(sRep);
        for (int i = tid; i < 480; i += 256) dst[i] = src[i];
    }
    __syncthreads();

    // ---- V compute: 1024 slots (b,h); emit fp16 B-frags (16 n's incl. zeros) ----
    #pragma unroll
    for (int i = 0; i < 4; ++i) {
        const int s = tid + i * 256;
        const int b = s >> 7, h = s & 127;
        const float* w3r = W3 + (size_t)h * 112;
        const float* rr = sRep + b * 240;
        float a0 = 0.f, a1 = 0.f, a2 = 0.f, a3 = 0.f, a4 = 0.f,
              a5 = 0.f, a6 = 0.f, a7 = 0.f, a8 = 0.f;
        #pragma unroll 4
        for (int m4 = 0; m4 < 16; ++m4) {            // l=0
            float4 w = *reinterpret_cast<const float4*>(w3r + m4 * 4);
            const float* wp = reinterpret_cast<const float*>(&w);
            #pragma unroll
            for (int c = 0; c < 4; ++c) a0 = fmaf(wp[c], rr[m4 * 4 + c], a0);
        }
        #pragma unroll 2
        for (int u4 = 0; u4 < 8; ++u4) {             // l=1
            float4 w = *reinterpret_cast<const float4*>(w3r + 64 + u4 * 4);
            const float* wp = reinterpret_cast<const float*>(&w);
            #pragma unroll
            for (int c = 0; c < 4; ++c) {
                int u = u4 * 4 + c;
                a1 = fmaf(wp[c], rr[64 + 3 * u + 0], a1);
                a2 = fmaf(wp[c], rr[64 + 3 * u + 1], a2);
                a3 = fmaf(wp[c], rr[64 + 3 * u + 2], a3);
            }
        }
        #pragma unroll 2
        for (int u4 = 0; u4 < 4; ++u4) {             // l=2
            float4 w = *reinterpret_cast<const float4*>(w3r + 96 + u4 * 4);
            const float* wp = reinterpret_cast<const float*>(&w);
            #pragma unroll
            for (int c = 0; c < 4; ++c) {
                int u = u4 * 4 + c;
                a4 = fmaf(wp[c], rr[160 + 5 * u + 0], a4);
                a5 = fmaf(wp[c], rr[160 + 5 * u + 1], a5);
                a6 = fmaf(wp[c], rr[160 + 5 * u + 2], a6);
                a7 = fmaf(wp[c], rr[160 + 5 * u + 3], a7);
                a8 = fmaf(wp[c], rr[160 + 5 * u + 4], a8);
            }
        }
        const float n0 = NORM0 * INV_SQRT_H, n1 = NORM1 * INV_SQRT_H, n2 = NORM2 * INV_SQRT_H;
        float vals[9];
        vals[0] = a0 * n0;
        vals[1] = a1 * n1; vals[2] = a2 * n1; vals[3] = a3 * n1;
        vals[4] = a4 * n2; vals[5] = a5 * n2; vals[6] = a6 * n2;
        vals[7] = a7 * n2; vals[8] = a8 * n2;
        // h = kt*32 + qd*8 + j ; frag pos = (b*4+kt)*512 + (qd*16+n)*8 + j
        const int kt = h >> 5, qd = (h >> 3) & 3, j = h & 7;
        _Float16* base = sVf + (b * 4 + kt) * 512 + qd * 128 + j;
        #pragma unroll
        for (int n = 0; n < 16; ++n)
            base[n * 8] = (n < 9) ? (_Float16)vals[n] : (_Float16)0.0f;
    }
    __syncthreads();   // sVf + sPos* ready; w2f writes drained (vmcnt 0 @ barrier)

    // ---- main loop: 4 passes x 2-b pairs (R8's proven structure) ----
    const int aLoc = wv * 16 + m;
    const float ax = sPosA[aLoc * 3 + 0];
    const float ay = sPosA[aLoc * 3 + 1];
    const float az = sPosA[aLoc * 3 + 2];
    float outAcc[4] = {0.f, 0.f, 0.f, 0.f};

    for (int pass = 0; pass < 4; ++pass) {
        const float* w1p0[2];
        const float* w1p1[2];
        float c0v[2], c1v[2];

        #pragma unroll
        for (int p = 0; p < 2; ++p) {
            const int bl = pass * 2 + p;
            const float bx = sPosB[bl * 3 + 0];
            const float by = sPosB[bl * 3 + 1];
            const float bz = sPosB[bl * 3 + 2];
            const float dx = ax - bx, dy = ay - by, dz = az - bz;
            const float r2 = dx * dx + dy * dy + dz * dz;
            const float r = sqrtf(fmaxf(r2, 1e-12f));
            const float nzf = (r2 > 1e-10f) ? 1.0f : 0.0f;
            const float ir = 1.0f / r;
            const float x = dx * ir, y = dy * ir, zz = dz * ir;
            if (quad == 0) {
                float4 g0, g1;
                g0.x = S3 * x * nzf; g0.y = S3 * y * nzf; g0.z = S3 * zz * nzf;
                g0.w = S15 * x * y * nzf;
                g1.x = S15 * y * zz * nzf;
                g1.y = 0.5f * S5 * (3.0f * zz * zz - 1.0f) * nzf;
                g1.z = S15 * x * zz * nzf;
                g1.w = 0.5f * S15 * (x * x - y * y) * nzf;
                *reinterpret_cast<float4*>(&sYw[wv][p][m][0]) = g0;
                *reinterpret_cast<float4*>(&sYw[wv][p][m][4]) = g1;
            }
            const float u = r * INV_STEP;
            int i0 = (int)floorf(u);
            const float d0 = u - (float)i0;
            float c0 = (i0 >= 0 && i0 < NB_) ? __cosf(HALF_PI * d0) : 0.f;
            const int i1 = i0 + 1;
            const float d1 = d0 - 1.0f;
            float c1 = (i1 >= 0 && i1 < NB_ && d1 > -1.0f) ? __cosf(HALF_PI * d1) : 0.f;
            const int i0c = min(max(i0, 0), NB_ - 1);
            const int i1c = min(max(i1, 0), NB_ - 1);
            w1p0[p] = W1 + i0c * H_;
            w1p1[p] = W1 + i1c * H_;
            c0v[p] = c0 * INV_SQRT_NB;
            c1v[p] = c1 * INV_SQRT_NB;
        }

        f32x4 acc[2][8];
        #pragma unroll
        for (int p = 0; p < 2; ++p)
            #pragma unroll
            for (int nt = 0; nt < 8; ++nt) {
                acc[p][nt][0] = 0.f; acc[p][nt][1] = 0.f;
                acc[p][nt][2] = 0.f; acc[p][nt][3] = 0.f;
            }

        // ---- layer1 (fp16 A-frag regs) + layer2 fp16 MFMA (B-frags via L1/L2) ----
        #pragma unroll
        for (int kt = 0; kt < 4; ++kt) {
            const int koff = kt * 32 + quad * 8;
            half8 ah[2];
            #pragma unroll
            for (int p = 0; p < 2; ++p) {
                float4 wa0 = *reinterpret_cast<const float4*>(w1p0[p] + koff);
                float4 wa1 = *reinterpret_cast<const float4*>(w1p0[p] + koff + 4);
                float4 wb0 = *reinterpret_cast<const float4*>(w1p1[p] + koff);
                float4 wb1 = *reinterpret_cast<const float4*>(w1p1[p] + koff + 4);
                const float* a0p = reinterpret_cast<const float*>(&wa0);
                const float* a1p = reinterpret_cast<const float*>(&wa1);
                const float* b0p = reinterpret_cast<const float*>(&wb0);
                const float* b1p = reinterpret_cast<const float*>(&wb1);
                #pragma unroll
                for (int j = 0; j < 8; ++j) {
                    float w0 = (j < 4) ? a0p[j] : a1p[j - 4];
                    float w1v = (j < 4) ? b0p[j] : b1p[j - 4];
                    ah[p][j] = (_Float16)ssp_f(fmaf(c0v[p], w0, c1v[p] * w1v));
                }
            }
            const _Float16* bhp = w2f + (size_t)(kt * 8) * 512 + (size_t)lane * 8;
            #pragma unroll
            for (int nt = 0; nt < 8; ++nt) {
                half8 bh = *reinterpret_cast<const half8*>(bhp + nt * 512);
                acc[0][nt] = __builtin_amdgcn_mfma_f32_16x16x32_f16(ah[0], bh, acc[0][nt], 0, 0, 0);
                acc[1][nt] = __builtin_amdgcn_mfma_f32_16x16x32_f16(ah[1], bh, acc[1][nt], 0, 0, 0);
            }
        }

        // ---- per-b epilogue ----
        #pragma unroll
        for (int p = 0; p < 2; ++p) {
            const int bl = pass * 2 + p;

            // ssp + per-kt fp16 transpose through wave-private LDS, combine
            f32x4 T0 = {0.f, 0.f, 0.f, 0.f};
            f32x4 T1 = {0.f, 0.f, 0.f, 0.f};
            #pragma unroll
            for (int kt = 0; kt < 4; ++kt) {
                #pragma unroll
                for (int ntl = 0; ntl < 2; ++ntl)
                    #pragma unroll
                    for (int reg = 0; reg < 4; ++reg)
                        sH2t[wv][quad * 4 + reg][ntl * 16 + m] =
                            (_Float16)ssp_f(acc[p][kt * 2 + ntl][reg] * INV_SQRT_H);
                half8 ah2 = *reinterpret_cast<const half8*>(&sH2t[wv][m][quad * 8]);
                half8 bv = *reinterpret_cast<const half8*>(sVf + (bl * 4 + kt) * 512 + lane * 8);
                if (kt & 1) T1 = __builtin_amdgcn_mfma_f32_16x16x32_f16(ah2, bv, T1, 0, 0, 0);
                else        T0 = __builtin_amdgcn_mfma_f32_16x16x32_f16(ah2, bv, T0, 0, 0, 0);
            }

            // G-weight; reduce DEFERRED: accumulate unreduced lane-partials
            const int comp = (m >= 1 && m <= 8) ? (m - 1) : 0;
            #pragma unroll
            for (int reg = 0; reg < 4; ++reg) {
                const int row = quad * 4 + reg;
                const float Tv = T0[reg] + T1[reg];
                const float yv = sYw[wv][p][row][comp];
                const float g = (m == 0) ? 1.0f : ((m <= 8) ? yv : 0.0f);
                outAcc[reg] = fmaf(Tv, g, outAcc[reg]);
            }
        }
    }

    // ---- single 16-lane shuffle reduce (hoisted out of the b loop) ----
    #pragma unroll
    for (int off = 1; off < 16; off <<= 1)
        #pragma unroll
        for (int reg = 0; reg < 4; ++reg)
            outAcc[reg] += __shfl_xor(outAcc[reg], off);

    // ---- write partial[z][bg][a]: lanes m==0 hold a = wv*16 + quad*4 + reg ----
    if (m == 0) {
        float4 st;
        st.x = outAcc[0]; st.y = outAcc[1]; st.z = outAcc[2]; st.w = outAcc[3];
        *reinterpret_cast<float4*>(partial + ((size_t)(z * 8 + bg)) * 64 + wv * 16 + quad * 4) = st;
    }
}

// ---------------------------------------------------------------------------
// finalize: out[z,a] = sp( (sum_bg partial) / sqrt(n_atoms) ) * mask
// ---------------------------------------------------------------------------
__global__ __launch_bounds__(64, 8)
void finalize(const float* __restrict__ partial, const float* __restrict__ mask,
              float* __restrict__ out) {
    const int z = blockIdx.x, a = threadIdx.x;
    const float mk = mask[z * 64 + a];
    float s = mk;
    #pragma unroll
    for (int off = 32; off > 0; off >>= 1) s += __shfl_xor(s, off);
    const float inv = rsqrtf(s);
    float acc = 0.f;
    #pragma unroll
    for (int bg = 0; bg < 8; ++bg)
        acc += partial[((size_t)(z * 8 + bg)) * 64 + a];
    out[z * 64 + a] = sp_f(acc * inv) * mk;
}

extern "C" void kernel_launch(void* const* d_in, const int* in_sizes, int n_in,
                              void* d_out, int out_size, void* d_ws, size_t ws_size,
                              hipStream_t stream) {
    const float* rep  = (const float*)d_in[0];
    const float* geom = (const float*)d_in[1];
    const float* mask = (const float*)d_in[2];
    const float* W1   = (const float*)d_in[3];
    const float* W2   = (const float*)d_in[4];
    const float* W3   = (const float*)d_in[5];
    float* out = (float*)d_out;

    _Float16* w2f = (_Float16*)d_ws;                          // 32768 B
    float* partial = (float*)((char*)d_ws + 32768);           // 512*64*4 = 131072 B

    pair4<<<dim3(8, 64), 256, 0, stream>>>(rep, geom, W1, W2, W3, w2f, partial);
    finalize<<<64, 64, 0, stream>>>(partial, mask, out);
}

// Round 12
// 116.212 us; speedup vs baseline: 1.1576x; 1.1576x over previous
//
#include <hip/hip_runtime.h>
#include <math.h>

// B=64, A=64, MULS=((64,0),(32,1),(16,2)) -> DIM_IN=240, NB=32, H=128, MOUT=112
#define H_ 128
#define NB_ 32

#define INV_STEP 3.1f
#define HALF_PI 1.57079632679489662f
#define INV_SQRT_NB 0.17677669529663689f
#define INV_SQRT_H 0.08838834764831845f
#define NORM0 0.125f
#define NORM1 0.10206207261596575f
#define NORM2 0.11180339887498948f
#define S3 1.7320508075688772f
#define S5 2.23606797749979f
#define S15 3.872983346207417f
#define LN2 0.6931471805599453f

// base-2 ssp refactor: u = 5*log2e*x ; ssp(x) = (max(u,0)+log2(1+2^-|u|)-1)*K
#define SSP_K 0.13862943611198906f          // ln2/5
#define C_L1SC 1.2751763f                   // INV_SQRT_NB * 5*log2(e)
#define C_EPSC 0.63758714f                  // INV_SQRT_H  * 5*log2(e)

typedef __attribute__((ext_vector_type(8))) _Float16 half8;
typedef __attribute__((ext_vector_type(4))) float f32x4;

__device__ __forceinline__ float ssp_u(float u) {
    // v_exp_f32 IS 2^x (|u| folds into input modifiers); v_log_f32 IS log2.
    float e = __builtin_amdgcn_exp2f(-fabsf(u));
    float l = __builtin_amdgcn_logf(1.0f + e);
    float r = fmaxf(u, 0.0f) + l;
    return fmaf(r, SSP_K, -SSP_K);
}
__device__ __forceinline__ float sp_f(float x) {
    float t = 5.0f * x;
    float s = fmaxf(t, 0.0f) + __logf(1.0f + __expf(-fabsf(t)));
    return s * 0.2f;
}

// ---------------------------------------------------------------------------
// pair4: Round-12 = R11 structure (2 launches, inline W2->fp16 staging to
// global ws, R8's proven main loop) + base-2 ssp instruction-count cut.
// Ledger: total = pair4 + ~53-55 µs fixed harness floor in EVERY round
// (R9's "30" was profiling inflation of its LDS-heavy pair4); launch surgery
// is exhausted. VALU-issue ~47-50 µs is the invariant floor -> delete insts:
//   - ssp: u = pre-scaled input; exp2(-|u|) (modifiers fold neg+abs);
//     log2(1+e); max; fma(K,-K). ~7 insts vs ~12; transcendentals identical.
//     Scale 5*log2e folded into c0v/c1v (layer1) and C_EPSC (epilogue).
//   - A-fragment f16 conversion via v_cvt_pkrtz (4 insts vs 8).
// Everything else byte-identical to R11.
// ---------------------------------------------------------------------------
__global__ __launch_bounds__(256, 2)
void pair4(const float* __restrict__ rep, const float* __restrict__ geom,
           const float* __restrict__ W1, const float* __restrict__ W2,
           const float* __restrict__ W3, _Float16* __restrict__ w2f,
           float* __restrict__ partial) {
    const int bg = blockIdx.x;           // b in [8bg, 8bg+8)
    const int z  = blockIdx.y;
    const int tid = threadIdx.x;
    const int wv = tid >> 6, lane = tid & 63;
    const int m = lane & 15, quad = lane >> 4;

    __shared__ __align__(16) _Float16 sVf[16384];      // 32768 B  [b<8][kt][lane][j]
    __shared__ __align__(16) _Float16 sH2t[4][16][40]; // 5120 B   per-wave [a][h2local+pad]
    __shared__ __align__(16) float sRep[1920];         // 7680 B   8 rep rows
    __shared__ float sYw[4][2][16][8];                 // 4096 B
    __shared__ float sPosA[192];                       // 768 B
    __shared__ float sPosB[24];                        // 96 B
    // total ~50.6 KB; reg-bound 2 blocks/CU

    // ---- W2 -> fp16 B-frags into global ws (every block, identical values) ----
    #pragma unroll
    for (int i = 0; i < 8; ++i) {
        const int pr = tid + i * 256;        // 0..2047
        const int ln = pr & 63, fn = pr >> 6;
        const int kt = fn >> 3, nt = fn & 7;
        const int krow = kt * 32 + (ln >> 4) * 8;
        const int n = nt * 16 + (ln & 15);
        const float* src = W2 + krow * 128 + n;
        half8 hv;
        #pragma unroll
        for (int j = 0; j < 8; ++j)
            hv[j] = (_Float16)src[j * 128];
        *reinterpret_cast<half8*>(w2f + (size_t)pr * 8) = hv;
    }

    // ---- startup: stage geom + rep ----
    if (tid < 192) sPosA[tid] = geom[z * 192 + tid];
    else if (tid < 216) sPosB[tid - 192] = geom[((size_t)z * 64 + bg * 8) * 3 + (tid - 192)];
    {
        const float4* src = reinterpret_cast<const float4*>(rep + ((size_t)z * 64 + bg * 8) * 240);
        float4* dst = reinterpret_cast<float4*>(sRep);
        for (int i = tid; i < 480; i += 256) dst[i] = src[i];
    }
    __syncthreads();

    // ---- V compute: 1024 slots (b,h); emit fp16 B-frags (16 n's incl. zeros) ----
    #pragma unroll
    for (int i = 0; i < 4; ++i) {
        const int s = tid + i * 256;
        const int b = s >> 7, h = s & 127;
        const float* w3r = W3 + (size_t)h * 112;
        const float* rr = sRep + b * 240;
        float a0 = 0.f, a1 = 0.f, a2 = 0.f, a3 = 0.f, a4 = 0.f,
              a5 = 0.f, a6 = 0.f, a7 = 0.f, a8 = 0.f;
        #pragma unroll 4
        for (int m4 = 0; m4 < 16; ++m4) {            // l=0
            float4 w = *reinterpret_cast<const float4*>(w3r + m4 * 4);
            const float* wp = reinterpret_cast<const float*>(&w);
            #pragma unroll
            for (int c = 0; c < 4; ++c) a0 = fmaf(wp[c], rr[m4 * 4 + c], a0);
        }
        #pragma unroll 2
        for (int u4 = 0; u4 < 8; ++u4) {             // l=1
            float4 w = *reinterpret_cast<const float4*>(w3r + 64 + u4 * 4);
            const float* wp = reinterpret_cast<const float*>(&w);
            #pragma unroll
            for (int c = 0; c < 4; ++c) {
                int u = u4 * 4 + c;
                a1 = fmaf(wp[c], rr[64 + 3 * u + 0], a1);
                a2 = fmaf(wp[c], rr[64 + 3 * u + 1], a2);
                a3 = fmaf(wp[c], rr[64 + 3 * u + 2], a3);
            }
        }
        #pragma unroll 2
        for (int u4 = 0; u4 < 4; ++u4) {             // l=2
            float4 w = *reinterpret_cast<const float4*>(w3r + 96 + u4 * 4);
            const float* wp = reinterpret_cast<const float*>(&w);
            #pragma unroll
            for (int c = 0; c < 4; ++c) {
                int u = u4 * 4 + c;
                a4 = fmaf(wp[c], rr[160 + 5 * u + 0], a4);
                a5 = fmaf(wp[c], rr[160 + 5 * u + 1], a5);
                a6 = fmaf(wp[c], rr[160 + 5 * u + 2], a6);
                a7 = fmaf(wp[c], rr[160 + 5 * u + 3], a7);
                a8 = fmaf(wp[c], rr[160 + 5 * u + 4], a8);
            }
        }
        const float n0 = NORM0 * INV_SQRT_H, n1 = NORM1 * INV_SQRT_H, n2 = NORM2 * INV_SQRT_H;
        float vals[9];
        vals[0] = a0 * n0;
        vals[1] = a1 * n1; vals[2] = a2 * n1; vals[3] = a3 * n1;
        vals[4] = a4 * n2; vals[5] = a5 * n2; vals[6] = a6 * n2;
        vals[7] = a7 * n2; vals[8] = a8 * n2;
        // h = kt*32 + qd*8 + j ; frag pos = (b*4+kt)*512 + (qd*16+n)*8 + j
        const int kt = h >> 5, qd = (h >> 3) & 3, j = h & 7;
        _Float16* base = sVf + (b * 4 + kt) * 512 + qd * 128 + j;
        #pragma unroll
        for (int n = 0; n < 16; ++n)
            base[n * 8] = (n < 9) ? (_Float16)vals[n] : (_Float16)0.0f;
    }
    __syncthreads();   // sVf + sPos* ready; w2f writes drained (vmcnt0 @ barrier)

    // ---- main loop: 4 passes x 2-b pairs (R8's proven structure) ----
    const int aLoc = wv * 16 + m;
    const float ax = sPosA[aLoc * 3 + 0];
    const float ay = sPosA[aLoc * 3 + 1];
    const float az = sPosA[aLoc * 3 + 2];
    float outAcc[4] = {0.f, 0.f, 0.f, 0.f};

    for (int pass = 0; pass < 4; ++pass) {
        const float* w1p0[2];
        const float* w1p1[2];
        float c0v[2], c1v[2];

        #pragma unroll
        for (int p = 0; p < 2; ++p) {
            const int bl = pass * 2 + p;
            const float bx = sPosB[bl * 3 + 0];
            const float by = sPosB[bl * 3 + 1];
            const float bz = sPosB[bl * 3 + 2];
            const float dx = ax - bx, dy = ay - by, dz = az - bz;
            const float r2 = dx * dx + dy * dy + dz * dz;
            const float r = sqrtf(fmaxf(r2, 1e-12f));
            const float nzf = (r2 > 1e-10f) ? 1.0f : 0.0f;
            const float ir = 1.0f / r;
            const float x = dx * ir, y = dy * ir, zz = dz * ir;
            if (quad == 0) {
                float4 g0, g1;
                g0.x = S3 * x * nzf; g0.y = S3 * y * nzf; g0.z = S3 * zz * nzf;
                g0.w = S15 * x * y * nzf;
                g1.x = S15 * y * zz * nzf;
                g1.y = 0.5f * S5 * (3.0f * zz * zz - 1.0f) * nzf;
                g1.z = S15 * x * zz * nzf;
                g1.w = 0.5f * S15 * (x * x - y * y) * nzf;
                *reinterpret_cast<float4*>(&sYw[wv][p][m][0]) = g0;
                *reinterpret_cast<float4*>(&sYw[wv][p][m][4]) = g1;
            }
            const float u = r * INV_STEP;
            int i0 = (int)floorf(u);
            const float d0 = u - (float)i0;
            float c0 = (i0 >= 0 && i0 < NB_) ? __cosf(HALF_PI * d0) : 0.f;
            const int i1 = i0 + 1;
            const float d1 = d0 - 1.0f;
            float c1 = (i1 >= 0 && i1 < NB_ && d1 > -1.0f) ? __cosf(HALF_PI * d1) : 0.f;
            const int i0c = min(max(i0, 0), NB_ - 1);
            const int i1c = min(max(i1, 0), NB_ - 1);
            w1p0[p] = W1 + i0c * H_;
            w1p1[p] = W1 + i1c * H_;
            // fold INV_SQRT_NB * 5*log2e into the basis coefficients: the
            // layer1 fma then produces u directly for base-2 ssp.
            c0v[p] = c0 * C_L1SC;
            c1v[p] = c1 * C_L1SC;
        }

        f32x4 acc[2][8];
        #pragma unroll
        for (int p = 0; p < 2; ++p)
            #pragma unroll
            for (int nt = 0; nt < 8; ++nt) {
                acc[p][nt][0] = 0.f; acc[p][nt][1] = 0.f;
                acc[p][nt][2] = 0.f; acc[p][nt][3] = 0.f;
            }

        // ---- layer1 (fp16 A-frag regs, base-2 ssp, pkrtz) + layer2 MFMA ----
        #pragma unroll
        for (int kt = 0; kt < 4; ++kt) {
            const int koff = kt * 32 + quad * 8;
            half8 ah[2];
            #pragma unroll
            for (int p = 0; p < 2; ++p) {
                float4 wa0 = *reinterpret_cast<const float4*>(w1p0[p] + koff);
                float4 wa1 = *reinterpret_cast<const float4*>(w1p0[p] + koff + 4);
                float4 wb0 = *reinterpret_cast<const float4*>(w1p1[p] + koff);
                float4 wb1 = *reinterpret_cast<const float4*>(w1p1[p] + koff + 4);
                const float* a0p = reinterpret_cast<const float*>(&wa0);
                const float* a1p = reinterpret_cast<const float*>(&wa1);
                const float* b0p = reinterpret_cast<const float*>(&wb0);
                const float* b1p = reinterpret_cast<const float*>(&wb1);
                #pragma unroll
                for (int j2 = 0; j2 < 4; ++j2) {
                    const int j = j2 * 2;
                    float w0a = (j < 4) ? a0p[j] : a1p[j - 4];
                    float w1a = (j < 4) ? b0p[j] : b1p[j - 4];
                    float w0b = (j + 1 < 4) ? a0p[j + 1] : a1p[j - 3];
                    float w1b = (j + 1 < 4) ? b0p[j + 1] : b1p[j - 3];
                    float ua = fmaf(c0v[p], w0a, c1v[p] * w1a);
                    float ub = fmaf(c0v[p], w0b, c1v[p] * w1b);
                    auto pk = __builtin_amdgcn_cvt_pkrtz(ssp_u(ua), ssp_u(ub));
                    ah[p][j] = pk[0];
                    ah[p][j + 1] = pk[1];
                }
            }
            const _Float16* bhp = w2f + (size_t)(kt * 8) * 512 + (size_t)lane * 8;
            #pragma unroll
            for (int nt = 0; nt < 8; ++nt) {
                half8 bh = *reinterpret_cast<const half8*>(bhp + nt * 512);
                acc[0][nt] = __builtin_amdgcn_mfma_f32_16x16x32_f16(ah[0], bh, acc[0][nt], 0, 0, 0);
                acc[1][nt] = __builtin_amdgcn_mfma_f32_16x16x32_f16(ah[1], bh, acc[1][nt], 0, 0, 0);
            }
        }

        // ---- per-b epilogue ----
        #pragma unroll
        for (int p = 0; p < 2; ++p) {
            const int bl = pass * 2 + p;

            // base-2 ssp + per-kt fp16 transpose through wave-private LDS
            f32x4 T0 = {0.f, 0.f, 0.f, 0.f};
            f32x4 T1 = {0.f, 0.f, 0.f, 0.f};
            #pragma unroll
            for (int kt = 0; kt < 4; ++kt) {
                #pragma unroll
                for (int ntl = 0; ntl < 2; ++ntl)
                    #pragma unroll
                    for (int reg = 0; reg < 4; ++reg)
                        sH2t[wv][quad * 4 + reg][ntl * 16 + m] =
                            (_Float16)ssp_u(acc[p][kt * 2 + ntl][reg] * C_EPSC);
                half8 ah2 = *reinterpret_cast<const half8*>(&sH2t[wv][m][quad * 8]);
                half8 bv = *reinterpret_cast<const half8*>(sVf + (bl * 4 + kt) * 512 + lane * 8);
                if (kt & 1) T1 = __builtin_amdgcn_mfma_f32_16x16x32_f16(ah2, bv, T1, 0, 0, 0);
                else        T0 = __builtin_amdgcn_mfma_f32_16x16x32_f16(ah2, bv, T0, 0, 0, 0);
            }

            // G-weight; reduce DEFERRED: accumulate unreduced lane-partials
            const int comp = (m >= 1 && m <= 8) ? (m - 1) : 0;
            #pragma unroll
            for (int reg = 0; reg < 4; ++reg) {
                const int row = quad * 4 + reg;
                const float Tv = T0[reg] + T1[reg];
                const float yv = sYw[wv][p][row][comp];
                const float g = (m == 0) ? 1.0f : ((m <= 8) ? yv : 0.0f);
                outAcc[reg] = fmaf(Tv, g, outAcc[reg]);
            }
        }
    }

    // ---- single 16-lane shuffle reduce (hoisted out of the b loop) ----
    #pragma unroll
    for (int off = 1; off < 16; off <<= 1)
        #pragma unroll
        for (int reg = 0; reg < 4; ++reg)
            outAcc[reg] += __shfl_xor(outAcc[reg], off);

    // ---- write partial[z][bg][a]: lanes m==0 hold a = wv*16 + quad*4 + reg ----
    if (m == 0) {
        float4 st;
        st.x = outAcc[0]; st.y = outAcc[1]; st.z = outAcc[2]; st.w = outAcc[3];
        *reinterpret_cast<float4*>(partial + ((size_t)(z * 8 + bg)) * 64 + wv * 16 + quad * 4) = st;
    }
}

// ---------------------------------------------------------------------------
// finalize: out[z,a] = sp( (sum_bg partial) / sqrt(n_atoms) ) * mask
// ---------------------------------------------------------------------------
__global__ __launch_bounds__(64, 8)
void finalize(const float* __restrict__ partial, const float* __restrict__ mask,
              float* __restrict__ out) {
    const int z = blockIdx.x, a = threadIdx.x;
    const float mk = mask[z * 64 + a];
    float s = mk;
    #pragma unroll
    for (int off = 32; off > 0; off >>= 1) s += __shfl_xor(s, off);
    const float inv = rsqrtf(s);
    float acc = 0.f;
    #pragma unroll
    for (int bg = 0; bg < 8; ++bg)
        acc += partial[((size_t)(z * 8 + bg)) * 64 + a];
    out[z * 64 + a] = sp_f(acc * inv) * mk;
}

extern "C" void kernel_launch(void* const* d_in, const int* in_sizes, int n_in,
                              void* d_out, int out_size, void* d_ws, size_t ws_size,
                              hipStream_t stream) {
    const float* rep  = (const float*)d_in[0];
    const float* geom = (const float*)d_in[1];
    const float* mask = (const float*)d_in[2];
    const float* W1   = (const float*)d_in[3];
    const float* W2   = (const float*)d_in[4];
    const float* W3   = (const float*)d_in[5];
    float* out = (float*)d_out;

    _Float16* w2f = (_Float16*)d_ws;                          // 32768 B
    float* partial = (float*)((char*)d_ws + 32768);           // 512*64*4 = 131072 B

    pair4<<<dim3(8, 64), 256, 0, stream>>>(rep, geom, W1, W2, W3, w2f, partial);
    finalize<<<64, 64, 0, stream>>>(partial, mask, out);
}